// Round 19
// baseline (822.086 us; speedup 1.0000x reference)
//
#include <hip/hip_runtime.h>

typedef __attribute__((ext_vector_type(8))) short short8;
typedef __attribute__((ext_vector_type(4))) short short4v;
typedef __attribute__((ext_vector_type(4))) float f32x4;
typedef __attribute__((ext_vector_type(16))) float f32x16;

#define NH 32
#define HS 128
#define CDIM 4096
#define QBLK 256
#define KVBLK 64
#define NQT 16  // T / QBLK

__device__ __forceinline__ ushort f2bf(float f) {
  union { float f; unsigned u; } a; a.f = f;
  unsigned u = a.u;
  return (ushort)((u + 0x7FFFu + ((u >> 16) & 1u)) >> 16);
}
__device__ __forceinline__ float bf2f(ushort h) {
  union { unsigned u; float f; } a; a.u = ((unsigned)h) << 16;
  return a.f;
}
__device__ __forceinline__ unsigned cvtpk_bf16(float lo, float hi) {
  unsigned r;
  asm("v_cvt_pk_bf16_f32 %0, %1, %2" : "=v"(r) : "v"(lo), "v"(hi));
  return r;
}

__device__ __forceinline__ void gld16(const void* g, void* l) {
  __builtin_amdgcn_global_load_lds((const __attribute__((address_space(1))) void*)g,
                                   (__attribute__((address_space(3))) void*)l, 16, 0, 0);
}

__device__ __forceinline__ unsigned lds_off(const void* p) {
  return (unsigned)(uintptr_t)(const __attribute__((address_space(3))) void*)p;
}

template<int OFF>
__device__ __forceinline__ short4v ds_tr16(unsigned addr) {
  short4v r;
  asm volatile("ds_read_b64_tr_b16 %0, %1 offset:%c2" : "=v"(r) : "v"(addr), "i"(OFF));
  return r;
}

// ---------------- fp32 -> bf16 casts ----------------
__global__ __launch_bounds__(256) void cast_bf16_kernel(const float* __restrict__ in,
                                                        ushort* __restrict__ out, int n4) {
  int i = blockIdx.x * 256 + threadIdx.x;
  if (i >= n4) return;
  float4 v = ((const float4*)in)[i];
  ushort4 o;
  o.x = f2bf(v.x); o.y = f2bf(v.y); o.z = f2bf(v.z); o.w = f2bf(v.w);
  ((ushort4*)out)[i] = o;
}

__global__ __launch_bounds__(256) void cast4_kernel(const float* __restrict__ s0,
                                                    const float* __restrict__ s1,
                                                    const float* __restrict__ s2,
                                                    const float* __restrict__ s3,
                                                    ushort* __restrict__ d0,
                                                    ushort* __restrict__ d1,
                                                    ushort* __restrict__ d2,
                                                    ushort* __restrict__ d3,
                                                    int segBlocks) {
  int b = blockIdx.x;
  int seg = b / segBlocks;
  int i = (b - seg * segBlocks) * 256 + threadIdx.x;
  const float* in = (seg == 0) ? s0 : (seg == 1) ? s1 : (seg == 2) ? s2 : s3;
  ushort* out = (seg == 0) ? d0 : (seg == 1) ? d1 : (seg == 2) ? d2 : d3;
  float4 v = ((const float4*)in)[i];
  ushort4 o;
  o.x = f2bf(v.x); o.y = f2bf(v.y); o.z = f2bf(v.z); o.w = f2bf(v.w);
  ((ushort4*)out)[i] = o;
}

// ---------------- GEMM 256x256 8-phase core (32x32x16 MFMA) ----------------
// Round-19: inner fragments switched 16x16x32 -> 32x32x16 (4061 vs 3378 FLOP/cy:
// 17% less MFMA-pipe time; m119). LDS layout, swizzle (cl = cg ^ (row&7)),
// staging, 8-phase schedule, vmcnt counts, hoisting all unchanged from r18.
// A/B frags: lane r32=l&31 -> row, k = (l>>5)*8+e within k-slice; any HW internal
// k-permutation applies identically to both operands (same convention) and
// cancels in the dot product. C/D map (HW-verified m74/m101):
//   col = lane&31, row = (reg&3) + 8*(reg>>2) + 4*(lane>>5).
#define A00 0
#define A01 16384
#define A10 32768
#define A11 49152
#define B00 65536
#define B01 81920
#define B10 98304
#define B11 114688

#define GEMM_BODY(OUT_STORE)                                                       \
  __shared__ char sm[131072];                                                      \
  const int tid = threadIdx.x;                                                     \
  const int w = tid >> 6, lane = tid & 63;                                         \
  const int r32 = lane & 31, hi = lane >> 5;                                       \
  const char* A0p = (const char*)(A + m0 * 4096);                                  \
  const char* A1p = A0p + 1048576;                                                 \
  const char* B0p = (const char*)(Bp + n0 * 4096);                                 \
  const char* B1p = B0p + 1048576;                                                 \
  const int i0 = tid, i1 = tid + 512;                                              \
  const int ri0 = i0 >> 3, ri1 = i1 >> 3;                                          \
  const int cg0 = (i0 & 7) ^ (ri0 & 7);                                            \
  const int cg1 = (i1 & 7) ^ (ri1 & 7);                                            \
  const int off0 = ri0 * 8192 + cg0 * 16;                                          \
  const int off1 = ri1 * 8192 + cg1 * 16;                                          \
  const unsigned sd0 = (unsigned)(w * 1024);                                       \
  const unsigned sd1 = (unsigned)(8192 + w * 1024);                                \
  const int sw32 = r32 & 7;                                                        \
  const unsigned rbase = (unsigned)(r32 * 128);                                    \
  unsigned rdk[4];                                                                 \
  _Pragma("unroll")                                                                \
  for (int ks_ = 0; ks_ < 4; ks_++)                                                \
    rdk[ks_] = (unsigned)((((ks_ * 2 + hi) ^ sw32) << 4));                         \
  const int wmg = w >> 2, wng = w & 3;                                             \
  const unsigned aE = wmg ? A01 : A00;                                             \
  const unsigned aO = wmg ? A11 : A10;                                             \
  const unsigned bE = (wng >> 1) ? B01 : B00;                                      \
  const unsigned bO = (wng >> 1) ? B11 : B10;                                      \
  const unsigned bco = (unsigned)((wng & 1) * 8192);                               \
  f32x16 acc[4][2] = {};                                                           \
  short8 af[2][4], u[4], v[4];                                                     \
  STG(B0p, 0, B00); STG(B1p, 0, B01); STG(A0p, 0, A00); STG(A1p, 0, A01);          \
  STG(B0p, 64, B10); STG(B1p, 64, B11); STG(A0p, 64, A10); STG(A1p, 64, A11);      \
  asm volatile("s_waitcnt vmcnt(8)" ::: "memory");                                 \
  __builtin_amdgcn_s_barrier();                                                    \
  __builtin_amdgcn_sched_barrier(0);                                               \
  for (int it = 0; it < 32; ++it) {                                                \
    const int kc = it * 128;                                                       \
    const bool st = (it < 31);                                                     \
    /* P1: quadrant (m0,n0) even tile */                                           \
    LDA32(aE, 0); LDB32(u, bE, 0);                                                 \
    BAR1; MM32(0, 0, u);                                                           \
    LDB32(v, bE, 1);                                                               \
    BAR2;                                                                          \
    /* P2: (m0,n1) */                                                              \
    if (st) STG(B0p, kc + 128, B00);                                               \
    BAR1; MM32(0, 1, v);                                                           \
    LDA32(aE, 1);                                                                  \
    BAR2;                                                                          \
    /* P3: (m1,n1) */                                                              \
    if (st) STG(B1p, kc + 128, B01);                                               \
    BAR1; MM32(1, 1, v); BAR2;                                                     \
    /* P4: (m1,n0); confirm odd tile */                                            \
    if (st) STG(A0p, kc + 128, A00);                                               \
    BAR1; MM32(1, 0, u);                                                           \
    __builtin_amdgcn_s_setprio(0);                                                 \
    if (st) asm volatile("s_waitcnt vmcnt(6)" ::: "memory");                       \
    else    asm volatile("s_waitcnt vmcnt(0)" ::: "memory");                       \
    __builtin_amdgcn_s_barrier();                                                  \
    /* P5: quadrant (m0,n0) odd tile */                                            \
    LDA32(aO, 0); LDB32(u, bO, 0);                                                 \
    if (st) STG(A1p, kc + 128, A01);                                               \
    BAR1; MM32(0, 0, u);                                                           \
    LDB32(v, bO, 1);                                                               \
    BAR2;                                                                          \
    /* P6: (m0,n1) */                                                              \
    if (st) STG(B0p, kc + 192, B10);                                               \
    BAR1; MM32(0, 1, v);                                                           \
    LDA32(aO, 1);                                                                  \
    BAR2;                                                                          \
    /* P7: (m1,n1) */                                                              \
    if (st) STG(B1p, kc + 192, B11);                                               \
    BAR1; MM32(1, 1, v); BAR2;                                                     \
    /* P8: (m1,n0); confirm even tile */                                           \
    if (st) { STG(A0p, kc + 192, A10); STG(A1p, kc + 192, A11); }                  \
    BAR1; MM32(1, 0, u);                                                           \
    __builtin_amdgcn_s_setprio(0);                                                 \
    if (st) asm volatile("s_waitcnt vmcnt(8)" ::: "memory");                       \
    __builtin_amdgcn_s_barrier();                                                  \
  }                                                                                \
  const int wm = wmg * 128, wn = wng * 64;                                         \
  _Pragma("unroll")                                                                \
  for (int mt_ = 0; mt_ < 4; mt_++) {                                              \
    _Pragma("unroll")                                                              \
    for (int nt_ = 0; nt_ < 2; nt_++) {                                            \
      const size_t col = n0 + wn + nt_ * 32 + r32;                                 \
      _Pragma("unroll")                                                            \
      for (int r = 0; r < 16; r++) {                                               \
        const size_t row = m0 + wm + mt_ * 32 + (r & 3) + 8 * (r >> 2) + 4 * hi;   \
        const float cv = acc[mt_][nt_][r];                                         \
        OUT_STORE;                                                                 \
      }                                                                            \
    }                                                                              \
  }

#define STG(PAN, K0, LB) do { \
    gld16((PAN) + (size_t)(K0) * 2 + off0, sm + (LB) + sd0); \
    gld16((PAN) + (size_t)(K0) * 2 + off1, sm + (LB) + sd1); \
  } while (0)
#define LDA32(BASE, MQ) do { _Pragma("unroll") for (int mf_ = 0; mf_ < 2; mf_++) \
    { _Pragma("unroll") for (int ks_ = 0; ks_ < 4; ks_++) \
      af[mf_][ks_] = *(const short8*)(sm + (BASE) + (MQ) * 8192 + mf_ * 4096 + rbase + rdk[ks_]); } } while (0)
#define LDB32(R, BASE, NQ) do { _Pragma("unroll") for (int ks_ = 0; ks_ < 4; ks_++) \
    R[ks_] = *(const short8*)(sm + (BASE) + bco + (NQ) * 4096 + rbase + rdk[ks_]); } while (0)
#define MM32(MQ, NQ, R) do { _Pragma("unroll") for (int ks_ = 0; ks_ < 4; ks_++) \
    { _Pragma("unroll") for (int mf_ = 0; mf_ < 2; mf_++) \
      acc[(MQ) * 2 + mf_][NQ] = __builtin_amdgcn_mfma_f32_32x32x16_bf16(af[mf_][ks_], R[ks_], acc[(MQ) * 2 + mf_][NQ], 0, 0, 0); } } while (0)
#define BAR1 do { __builtin_amdgcn_s_barrier(); \
    __builtin_amdgcn_s_setprio(1); } while (0)
#define BAR2 do { __builtin_amdgcn_s_setprio(0); __builtin_amdgcn_s_barrier(); } while (0)

// Fused QKV projection: segment-ordered (bid 0-255 Q, 256-511 K, 512-767 V).
__global__ __launch_bounds__(512, 2) void gemm_qkv(const ushort* __restrict__ A,
                                                   const ushort* __restrict__ Bq,
                                                   const ushort* __restrict__ Bk,
                                                   const ushort* __restrict__ Bv,
                                                   ushort* __restrict__ Cq,
                                                   ushort* __restrict__ Ck,
                                                   ushort* __restrict__ Cv) {
  const int bid = blockIdx.x;
  const int seg = bid >> 8;
  const int lb = bid & 255;
  const int x = (lb & 7) * 32 + (lb >> 3);
  const int mt = x >> 4, ntl = x & 15;
  const ushort* Bp;
  ushort* Cp;
  if (seg == 0)      { Bp = Bq; Cp = Cq; }
  else if (seg == 1) { Bp = Bk; Cp = Ck; }
  else               { Bp = Bv; Cp = Cv; }
  const size_t m0 = (size_t)mt * 256, n0 = (size_t)ntl * 256;
  GEMM_BODY(Cp[row * 4096 + col] = f2bf(cv));
}

// Single GEMM (final O-projection, fp32 out).
__global__ __launch_bounds__(512, 2) void gemm256f(const ushort* __restrict__ A,
                                                   const ushort* __restrict__ Bp,
                                                   float* __restrict__ C) {
  const int bid = blockIdx.x;
  const int x = (bid & 7) * 32 + (bid >> 3);
  const int mt = x >> 4, nt = x & 15;
  const size_t m0 = (size_t)mt * 256, n0 = (size_t)nt * 256;
  GEMM_BODY(C[row * 4096 + col] = cv);
}

#undef STG
#undef LDA32
#undef LDB32
#undef MM32
#undef BAR1
#undef BAR2

// ---------------- RoPE (in-place on Q and K, bf16) ----------------
__global__ __launch_bounds__(256) void rope_kernel(ushort* __restrict__ Q,
                                                   ushort* __restrict__ Kb,
                                                   const int* __restrict__ pos_ids,
                                                   int nrows) {
  int gid = blockIdx.x * 256 + threadIdx.x;
  int d = gid & 63;
  int row = gid >> 6;
  if (row >= nrows) return;
  int t = row >> 5;
  int pos = pos_ids[t];
  float inv = expf((float)d * -0.14391156831212788f);  // -ln(10000)/64
  float ang = (float)pos * inv;
  float s, c;
  sincosf(ang, &s, &c);
  size_t base = (size_t)row * HS;
  {
    float x1 = bf2f(Q[base + d]), x2 = bf2f(Q[base + d + 64]);
    Q[base + d]      = f2bf(x1 * c - x2 * s);
    Q[base + d + 64] = f2bf(x2 * c + x1 * s);
  }
  {
    float x1 = bf2f(Kb[base + d]), x2 = bf2f(Kb[base + d + 64]);
    Kb[base + d]      = f2bf(x1 * c - x2 * s);
    Kb[base + d + 64] = f2bf(x2 * c + x1 * s);
  }
}

// ---------------- Causal flash attention (v9, round-15 verified) ----------------
__global__ __launch_bounds__(512) void flash_attn(const ushort* __restrict__ Q,
                                                  const ushort* __restrict__ K,
                                                  const ushort* __restrict__ V,
                                                  ushort* __restrict__ O) {
  __shared__ __align__(16) ushort Ks[2][KVBLK * HS];
  __shared__ __align__(16) ushort Vs[2][KVBLK * HS];
  __shared__ __align__(16) ushort Ps[8][32 * 72];   // per-wave P^T tile: 32 rows x 144 B
  const int tid = threadIdx.x;
  const int w = tid >> 6, l = tid & 63, lhi = l >> 4, llo = l & 15;
  const int qbp = blockIdx.x, h = blockIdx.y;

  // tr-read per-lane constants (V path)
  const int g = llo >> 2, c = llo & 3;
  const int swz = g | ((lhi & 1) << 2);
  const int c1 = c >> 1;
  const int swL = swz & 1, swH = swz & 6;
  const unsigned trconst = (unsigned)((lhi * 8 + g) * 256 + ((c1 ^ swL) << 4) + (c & 1) * 8);

  // gld_lds staging constants
  const int r0 = w * 4 + lhi;
  const int cgK = llo ^ (r0 & 7);
  const int cgV = llo ^ ((r0 & 3) | (((r0 >> 3) & 1) << 2));

  char* pwB = (char*)Ps[w];
  const float scale = 0.08838834764831845f;  // 1/sqrt(128)

#define STAGE(T1) do { \
    const ushort* kp_ = K + (size_t)((T1) * KVBLK + r0) * CDIM + h * HS + cgK * 8; \
    const ushort* vp_ = V + (size_t)((T1) * KVBLK + r0) * CDIM + h * HS + cgV * 8; \
    char* kd_ = (char*)Ks[(T1) & 1] + w * 1024; \
    char* vd_ = (char*)Vs[(T1) & 1] + w * 1024; \
    gld16(kp_, kd_); gld16(kp_ + (size_t)32 * CDIM, kd_ + 8192); \
    gld16(vp_, vd_); gld16(vp_ + (size_t)32 * CDIM, vd_ + 8192); \
  } while (0)

  for (int ph = 0; ph < 2; ph++) {
    const int qt = ph ? (NQT - 1 - qbp) : qbp;
    const int qr0 = qt * QBLK + w * 32;
    const int ntile = 4 * qt + 4;

    short8 aq[2][4];
#pragma unroll
    for (int mf = 0; mf < 2; mf++) {
      const ushort* qp = Q + (size_t)(qr0 + mf * 16 + llo) * CDIM + h * HS + lhi * 8;
#pragma unroll
      for (int ki = 0; ki < 4; ki++) aq[mf][ki] = *(const short8*)(qp + ki * 32);
    }

    f32x4 acc[2][8] = {};
    float mrow[2] = {-1e30f, -1e30f};
    float lrow[2] = {0.f, 0.f};

    STAGE(0);
    __syncthreads();

    for (int t = 0; t < ntile; t++) {
      const int kv0 = t * KVBLK;
      if (t + 1 < ntile) STAGE(t + 1);

      const bool active = (kv0 <= qr0 + 31);
      if (active) {
        const char* ksB = (const char*)Ks[t & 1];
        const unsigned trb = lds_off(Vs[t & 1]) + trconst;

        // ---- S^T = K Q^T ----
        f32x4 s[2][4];
        __builtin_amdgcn_s_setprio(1);
#pragma unroll
        for (int nt = 0; nt < 4; nt++) {
          const int krow = nt * 16 + llo;
          const char* kr = ksB + krow * 256;
          short8 kf[4];
#pragma unroll
          for (int ki = 0; ki < 4; ki++)
            kf[ki] = *(const short8*)(kr + (((ki * 4 + lhi) ^ (krow & 7)) << 4));
          f32x4 s0 = {0.f, 0.f, 0.f, 0.f}, s1 = {0.f, 0.f, 0.f, 0.f};
#pragma unroll
          for (int ki = 0; ki < 4; ki++) {
            s0 = __builtin_amdgcn_mfma_f32_16x16x32_bf16(kf[ki], aq[0][ki], s0, 0, 0, 0);
            s1 = __builtin_amdgcn_mfma_f32_16x16x32_bf16(kf[ki], aq[1][ki], s1, 0, 0, 0);
          }
          s[0][nt] = s0; s[1][nt] = s1;
        }
        __builtin_amdgcn_s_setprio(0);

        // hoist V^T tr-reads for kv-block b=0
        short4v vl0[8], vh0[8];
#pragma unroll
        for (int on = 0; on < 8; on++) {
          unsigned a = trb + (unsigned)(((on * 2) ^ swH) << 4);
          vl0[on] = ds_tr16<0>(a);
          vh0[on] = ds_tr16<1024>(a);
        }

        // ---- scale + causal mask ----
        const bool needm = (kv0 + KVBLK - 1 > qr0);
#pragma unroll
        for (int mf = 0; mf < 2; mf++) {
          const int qi = qr0 + mf * 16 + llo;
#pragma unroll
          for (int nt = 0; nt < 4; nt++) {
            const int kvb = kv0 + nt * 16 + lhi * 4;
#pragma unroll
            for (int j = 0; j < 4; j++) {
              float sv = s[mf][nt][j] * scale;
              if (needm && kvb + j > qi) sv = -1e30f;
              s[mf][nt][j] = sv;
            }
          }
        }

        // ---- softmax: in-register row reduce + 2 shfl; defer-max ----
#pragma unroll
        for (int mf = 0; mf < 2; mf++) {
          f32x4 mm;
#pragma unroll
          for (int j = 0; j < 4; j++)
            mm[j] = fmaxf(fmaxf(s[mf][0][j], s[mf][1][j]), fmaxf(s[mf][2][j], s[mf][3][j]));
          float pmax = fmaxf(fmaxf(mm[0], mm[1]), fmaxf(mm[2], mm[3]));
          pmax = fmaxf(pmax, __shfl_xor(pmax, 16));
          pmax = fmaxf(pmax, __shfl_xor(pmax, 32));
          if (__any(pmax > mrow[mf] + 8.f)) {
            float mn = fmaxf(mrow[mf], pmax);
            float sc = __expf(mrow[mf] - mn);
            mrow[mf] = mn;
            lrow[mf] *= sc;
#pragma unroll
            for (int on = 0; on < 8; on++)
#pragma unroll
              for (int j = 0; j < 4; j++) acc[mf][on][j] *= sc;
          }
          float rs = 0.f;
#pragma unroll
          for (int nt = 0; nt < 4; nt++) {
            float p0 = __expf(s[mf][nt][0] - mrow[mf]);
            float p1 = __expf(s[mf][nt][1] - mrow[mf]);
            float p2 = __expf(s[mf][nt][2] - mrow[mf]);
            float p3 = __expf(s[mf][nt][3] - mrow[mf]);
            rs += (p0 + p1) + (p2 + p3);
            uint2 pk;
            pk.x = cvtpk_bf16(p0, p1);
            pk.y = cvtpk_bf16(p2, p3);
            *(uint2*)(pwB + (mf * 16 + llo) * 144 + nt * 32 + lhi * 8) = pk;
          }
          rs += __shfl_xor(rs, 16);
          rs += __shfl_xor(rs, 32);
          lrow[mf] += rs;
        }

        // ---- O^T += V^T P^T ----
        {
          short8 pf0 = *(const short8*)(pwB + llo * 144 + lhi * 16);
          short8 pf1 = *(const short8*)(pwB + (16 + llo) * 144 + lhi * 16);
          asm volatile("s_waitcnt lgkmcnt(0)" ::: "memory");
          __builtin_amdgcn_sched_barrier(0);
          __builtin_amdgcn_s_setprio(1);
#pragma unroll
          for (int on = 0; on < 8; on++) {
            short8 vf = __builtin_shufflevector(vl0[on], vh0[on], 0, 1, 2, 3, 4, 5, 6, 7);
            acc[0][on] = __builtin_amdgcn_mfma_f32_16x16x32_bf16(vf, pf0, acc[0][on], 0, 0, 0);
            acc[1][on] = __builtin_amdgcn_mfma_f32_16x16x32_bf16(vf, pf1, acc[1][on], 0, 0, 0);
          }
          __builtin_amdgcn_s_setprio(0);
        }
        {
          short8 pf0 = *(const short8*)(pwB + llo * 144 + 64 + lhi * 16);
          short8 pf1 = *(const short8*)(pwB + (16 + llo) * 144 + 64 + lhi * 16);
          short4v vl[8], vh[8];
#pragma unroll
          for (int on = 0; on < 8; on++) {
            unsigned a = trb + (unsigned)(((on * 2) ^ swH) << 4);
            vl[on] = ds_tr16<8192>(a);
            vh[on] = ds_tr16<9216>(a);
          }
          asm volatile("s_waitcnt lgkmcnt(0)" ::: "memory");
          __builtin_amdgcn_sched_barrier(0);
          __builtin_amdgcn_s_setprio(1);
#pragma unroll
          for (int on = 0; on < 8; on++) {
            short8 vf = __builtin_shufflevector(vl[on], vh[on], 0, 1, 2, 3, 4, 5, 6, 7);
            acc[0][on] = __builtin_amdgcn_mfma_f32_16x16x32_bf16(vf, pf0, acc[0][on], 0, 0, 0);
            acc[1][on] = __builtin_amdgcn_mfma_f32_16x16x32_bf16(vf, pf1, acc[1][on], 0, 0, 0);
          }
          __builtin_amdgcn_s_setprio(0);
        }
      }  // active

      __syncthreads();  // drains gld16 vmcnt + all LDS reads; next iter swaps buffers
    }

    // ---- epilogue ----
#pragma unroll
    for (int mf = 0; mf < 2; mf++) {
      const float ri = 1.0f / lrow[mf];
      ushort* orow = O + (size_t)(qr0 + mf * 16 + llo) * CDIM + h * HS + lhi * 4;
#pragma unroll
      for (int on = 0; on < 8; on++) {
        ushort4 o4;
        o4.x = f2bf(acc[mf][on][0] * ri);
        o4.y = f2bf(acc[mf][on][1] * ri);
        o4.z = f2bf(acc[mf][on][2] * ri);
        o4.w = f2bf(acc[mf][on][3] * ri);
        *(ushort4*)(orow + on * 16) = o4;
      }
    }
  }  // phase
#undef STAGE
}

// ---------------- launch ----------------
extern "C" void kernel_launch(void* const* d_in, const int* in_sizes, int n_in,
                              void* d_out, int out_size, void* d_ws, size_t ws_size,
                              hipStream_t stream) {
  const float* hs = (const float*)d_in[0];
  const int* pos = (const int*)d_in[1];
  const float* Wq = (const float*)d_in[2];
  const float* Wk = (const float*)d_in[3];
  const float* Wv = (const float*)d_in[4];
  const float* Wo = (const float*)d_in[5];
  float* out = (float*)d_out;

  const int T = 4096;
  const size_t elems = (size_t)T * CDIM;

  ushort* hsb  = (ushort*)d_ws;      // also attention output
  ushort* wbuf = hsb + elems;        // Wq bf16 / later Wo bf16
  ushort* qb   = wbuf + elems;
  ushort* kb   = qb + elems;
  ushort* vb   = kb + elems;

  // Wk/Wv bf16 scratch inside d_out (overwritten by the final GEMM)
  ushort* wkb = (ushort*)d_out;            // 32 MB
  ushort* wvb = wkb + elems;               // 32 MB

  const int n4 = (int)(elems / 4);
  const int castBlocks = (n4 + 255) / 256;

  cast4_kernel<<<castBlocks * 4, 256, 0, stream>>>(hs, Wq, Wk, Wv, hsb, wbuf, wkb, wvb, castBlocks);

  gemm_qkv<<<768, 512, 0, stream>>>(hsb, wbuf, wkb, wvb, qb, kb, vb);

  rope_kernel<<<(T * NH * 64) / 256, 256, 0, stream>>>(qb, kb, pos, T * NH);

  flash_attn<<<dim3(NQT / 2, NH), 512, 0, stream>>>(qb, kb, vb, hsb);

  cast_bf16_kernel<<<castBlocks, 256, 0, stream>>>(Wo, wbuf, n4);
  gemm256f<<<256, 512, 0, stream>>>(hsb, wbuf, out);
}

// Round 20
// 758.260 us; speedup vs baseline: 1.0842x; 1.0842x over previous
//
#include <hip/hip_runtime.h>

typedef __attribute__((ext_vector_type(8))) short short8;
typedef __attribute__((ext_vector_type(4))) short short4v;
typedef __attribute__((ext_vector_type(4))) float f32x4;

#define NH 32
#define HS 128
#define CDIM 4096
#define QBLK 256
#define KVBLK 64
#define NQT 16  // T / QBLK

__device__ __forceinline__ ushort f2bf(float f) {
  union { float f; unsigned u; } a; a.f = f;
  unsigned u = a.u;
  return (ushort)((u + 0x7FFFu + ((u >> 16) & 1u)) >> 16);
}
__device__ __forceinline__ float bf2f(ushort h) {
  union { unsigned u; float f; } a; a.u = ((unsigned)h) << 16;
  return a.f;
}
__device__ __forceinline__ unsigned cvtpk_bf16(float lo, float hi) {
  unsigned r;
  asm("v_cvt_pk_bf16_f32 %0, %1, %2" : "=v"(r) : "v"(lo), "v"(hi));
  return r;
}

__device__ __forceinline__ void gld16(const void* g, void* l) {
  __builtin_amdgcn_global_load_lds((const __attribute__((address_space(1))) void*)g,
                                   (__attribute__((address_space(3))) void*)l, 16, 0, 0);
}

__device__ __forceinline__ unsigned lds_off(const void* p) {
  return (unsigned)(uintptr_t)(const __attribute__((address_space(3))) void*)p;
}

template<int OFF>
__device__ __forceinline__ short4v ds_tr16(unsigned addr) {
  short4v r;
  asm volatile("ds_read_b64_tr_b16 %0, %1 offset:%c2" : "=v"(r) : "v"(addr), "i"(OFF));
  return r;
}

// ---------------- fp32 -> bf16 casts ----------------
__global__ __launch_bounds__(256) void cast_bf16_kernel(const float* __restrict__ in,
                                                        ushort* __restrict__ out, int n4) {
  int i = blockIdx.x * 256 + threadIdx.x;
  if (i >= n4) return;
  float4 v = ((const float4*)in)[i];
  ushort4 o;
  o.x = f2bf(v.x); o.y = f2bf(v.y); o.z = f2bf(v.z); o.w = f2bf(v.w);
  ((ushort4*)out)[i] = o;
}

__global__ __launch_bounds__(256) void cast4_kernel(const float* __restrict__ s0,
                                                    const float* __restrict__ s1,
                                                    const float* __restrict__ s2,
                                                    const float* __restrict__ s3,
                                                    ushort* __restrict__ d0,
                                                    ushort* __restrict__ d1,
                                                    ushort* __restrict__ d2,
                                                    ushort* __restrict__ d3,
                                                    int segBlocks) {
  int b = blockIdx.x;
  int seg = b / segBlocks;
  int i = (b - seg * segBlocks) * 256 + threadIdx.x;
  const float* in = (seg == 0) ? s0 : (seg == 1) ? s1 : (seg == 2) ? s2 : s3;
  ushort* out = (seg == 0) ? d0 : (seg == 1) ? d1 : (seg == 2) ? d2 : d3;
  float4 v = ((const float4*)in)[i];
  ushort4 o;
  o.x = f2bf(v.x); o.y = f2bf(v.y); o.z = f2bf(v.z); o.w = f2bf(v.w);
  ((ushort4*)out)[i] = o;
}

// ---------------- GEMM 256x256 8-phase core (round-18 verified: best state) ----------------
// 16x16x32 MFMA. Swizzle cl = cg ^ (row & 7) (bank conflicts = 0).
// ds_reads for P2/P3/P6/P7 hoisted into the previous phase after its MFMA cluster;
// staging 2 gld16/phase; vmcnt(6)@P4 / vmcnt(8)@P8.
// NOTE (round 19 post-mortem): 32x32x16 conversion regressed — its lane->row read
// map reintroduced 3.77e7 bank conflicts. Keep 16x16.
#define A00 0
#define A01 16384
#define A10 32768
#define A11 49152
#define B00 65536
#define B01 81920
#define B10 98304
#define B11 114688

#define GEMM_BODY(OUT_STORE)                                                       \
  __shared__ char sm[131072];                                                      \
  const int tid = threadIdx.x;                                                     \
  const int w = tid >> 6, lane = tid & 63, lhi = lane >> 4, llo = lane & 15;       \
  const char* A0p = (const char*)(A + m0 * 4096);                                  \
  const char* A1p = A0p + 1048576;                                                 \
  const char* B0p = (const char*)(Bp + n0 * 4096);                                 \
  const char* B1p = B0p + 1048576;                                                 \
  const int i0 = tid, i1 = tid + 512;                                              \
  const int ri0 = i0 >> 3, ri1 = i1 >> 3;                                          \
  const int cg0 = (i0 & 7) ^ (ri0 & 7);                                            \
  const int cg1 = (i1 & 7) ^ (ri1 & 7);                                            \
  const int off0 = ri0 * 8192 + cg0 * 16;                                          \
  const int off1 = ri1 * 8192 + cg1 * 16;                                          \
  const unsigned sd0 = (unsigned)(w * 1024);                                       \
  const unsigned sd1 = (unsigned)(8192 + w * 1024);                                \
  const int sw = llo & 7;                                                          \
  const unsigned rd0 = (unsigned)(llo * 128 + (((0 * 4 + lhi) ^ sw) << 4));        \
  const unsigned rd1 = (unsigned)(llo * 128 + (((1 * 4 + lhi) ^ sw) << 4));        \
  const int wmg = w >> 2, wng = w & 3;                                             \
  const unsigned aE = wmg ? A01 : A00;                                             \
  const unsigned aO = wmg ? A11 : A10;                                             \
  const unsigned bE = (wng >> 1) ? B01 : B00;                                      \
  const unsigned bO = (wng >> 1) ? B11 : B10;                                      \
  const unsigned bco = (unsigned)((wng & 1) * 8192);                               \
  f32x4 acc[8][4] = {};                                                            \
  short8 a0[4], a1[4], u0[2], u1[2], v0[2], v1[2];                                 \
  STG(B0p, 0, B00); STG(B1p, 0, B01); STG(A0p, 0, A00); STG(A1p, 0, A01);          \
  STG(B0p, 64, B10); STG(B1p, 64, B11); STG(A0p, 64, A10); STG(A1p, 64, A11);      \
  asm volatile("s_waitcnt vmcnt(8)" ::: "memory");                                 \
  __builtin_amdgcn_s_barrier();                                                    \
  __builtin_amdgcn_sched_barrier(0);                                               \
  for (int it = 0; it < 32; ++it) {                                                \
    const int kc = it * 128;                                                       \
    const bool st = (it < 31);                                                     \
    /* P1 */                                                                       \
    LDA(aE, 0); LDB(u0, u1, bE, 0);                                                \
    BAR1; MM(0, 0, u0, u1);                                                        \
    LDB(v0, v1, bE, 1);                                                            \
    BAR2;                                                                          \
    /* P2 */                                                                       \
    if (st) STG(B0p, kc + 128, B00);                                               \
    BAR1; MM(0, 1, v0, v1);                                                        \
    LDA(aE, 1);                                                                    \
    BAR2;                                                                          \
    /* P3 */                                                                       \
    if (st) STG(B1p, kc + 128, B01);                                               \
    BAR1; MM(1, 1, v0, v1); BAR2;                                                  \
    /* P4 */                                                                       \
    if (st) STG(A0p, kc + 128, A00);                                               \
    BAR1; MM(1, 0, u0, u1);                                                        \
    __builtin_amdgcn_s_setprio(0);                                                 \
    if (st) asm volatile("s_waitcnt vmcnt(6)" ::: "memory");                       \
    else    asm volatile("s_waitcnt vmcnt(0)" ::: "memory");                       \
    __builtin_amdgcn_s_barrier();                                                  \
    /* P5 */                                                                       \
    LDA(aO, 0); LDB(u0, u1, bO, 0);                                                \
    if (st) STG(A1p, kc + 128, A01);                                               \
    BAR1; MM(0, 0, u0, u1);                                                        \
    LDB(v0, v1, bO, 1);                                                            \
    BAR2;                                                                          \
    /* P6 */                                                                       \
    if (st) STG(B0p, kc + 192, B10);                                               \
    BAR1; MM(0, 1, v0, v1);                                                        \
    LDA(aO, 1);                                                                    \
    BAR2;                                                                          \
    /* P7 */                                                                       \
    if (st) STG(B1p, kc + 192, B11);                                               \
    BAR1; MM(1, 1, v0, v1); BAR2;                                                  \
    /* P8 */                                                                       \
    if (st) { STG(A0p, kc + 192, A10); STG(A1p, kc + 192, A11); }                  \
    BAR1; MM(1, 0, u0, u1);                                                        \
    __builtin_amdgcn_s_setprio(0);                                                 \
    if (st) asm volatile("s_waitcnt vmcnt(8)" ::: "memory");                       \
    __builtin_amdgcn_s_barrier();                                                  \
  }                                                                                \
  const int wm = wmg * 128, wn = wng * 64;                                         \
  _Pragma("unroll")                                                                \
  for (int m = 0; m < 8; m++) {                                                    \
    _Pragma("unroll")                                                              \
    for (int nf = 0; nf < 4; nf++) {                                               \
      const size_t col = n0 + wn + nf * 16 + llo;                                  \
      _Pragma("unroll")                                                            \
      for (int j = 0; j < 4; j++) {                                                \
        const size_t row = m0 + wm + m * 16 + lhi * 4 + j;                         \
        OUT_STORE;                                                                 \
      }                                                                            \
    }                                                                              \
  }

#define STG(PAN, K0, LB) do { \
    gld16((PAN) + (size_t)(K0) * 2 + off0, sm + (LB) + sd0); \
    gld16((PAN) + (size_t)(K0) * 2 + off1, sm + (LB) + sd1); \
  } while (0)
#define LDA(BASE, MQ) do { _Pragma("unroll") for (int m_ = 0; m_ < 4; m_++) { \
    a0[m_] = *(const short8*)(sm + (BASE) + (MQ) * 8192 + m_ * 2048 + rd0); \
    a1[m_] = *(const short8*)(sm + (BASE) + (MQ) * 8192 + m_ * 2048 + rd1); } } while (0)
#define LDB(R0, R1, BASE, NQ) do { _Pragma("unroll") for (int n_ = 0; n_ < 2; n_++) { \
    R0[n_] = *(const short8*)(sm + (BASE) + bco + (NQ) * 4096 + n_ * 2048 + rd0); \
    R1[n_] = *(const short8*)(sm + (BASE) + bco + (NQ) * 4096 + n_ * 2048 + rd1); } } while (0)
#define MM(MQ, NQ, R0, R1) do { \
    _Pragma("unroll") for (int m_ = 0; m_ < 4; m_++) _Pragma("unroll") for (int n_ = 0; n_ < 2; n_++) \
      acc[(MQ) * 4 + m_][(NQ) * 2 + n_] = __builtin_amdgcn_mfma_f32_16x16x32_bf16(a0[m_], R0[n_], acc[(MQ) * 4 + m_][(NQ) * 2 + n_], 0, 0, 0); \
    _Pragma("unroll") for (int m_ = 0; m_ < 4; m_++) _Pragma("unroll") for (int n_ = 0; n_ < 2; n_++) \
      acc[(MQ) * 4 + m_][(NQ) * 2 + n_] = __builtin_amdgcn_mfma_f32_16x16x32_bf16(a1[m_], R1[n_], acc[(MQ) * 4 + m_][(NQ) * 2 + n_], 0, 0, 0); \
  } while (0)
#define BAR1 do { __builtin_amdgcn_s_barrier(); \
    __builtin_amdgcn_s_setprio(1); } while (0)
#define BAR2 do { __builtin_amdgcn_s_setprio(0); __builtin_amdgcn_s_barrier(); } while (0)

// Fused QKV projection: segment-ordered (bid 0-255 Q, 256-511 K, 512-767 V).
__global__ __launch_bounds__(512, 2) void gemm_qkv(const ushort* __restrict__ A,
                                                   const ushort* __restrict__ Bq,
                                                   const ushort* __restrict__ Bk,
                                                   const ushort* __restrict__ Bv,
                                                   ushort* __restrict__ Cq,
                                                   ushort* __restrict__ Ck,
                                                   ushort* __restrict__ Cv) {
  const int bid = blockIdx.x;
  const int seg = bid >> 8;
  const int lb = bid & 255;
  const int x = (lb & 7) * 32 + (lb >> 3);
  const int mt = x >> 4, ntl = x & 15;
  const ushort* Bp;
  ushort* Cp;
  if (seg == 0)      { Bp = Bq; Cp = Cq; }
  else if (seg == 1) { Bp = Bk; Cp = Ck; }
  else               { Bp = Bv; Cp = Cv; }
  const size_t m0 = (size_t)mt * 256, n0 = (size_t)ntl * 256;
  GEMM_BODY(Cp[row * 4096 + col] = f2bf(acc[m][nf][j]));
}

// Single GEMM (final O-projection, fp32 out).
__global__ __launch_bounds__(512, 2) void gemm256f(const ushort* __restrict__ A,
                                                   const ushort* __restrict__ Bp,
                                                   float* __restrict__ C) {
  const int bid = blockIdx.x;
  const int x = (bid & 7) * 32 + (bid >> 3);
  const int mt = x >> 4, nt = x & 15;
  const size_t m0 = (size_t)mt * 256, n0 = (size_t)nt * 256;
  GEMM_BODY(C[row * 4096 + col] = acc[m][nf][j]);
}

#undef STG
#undef LDA
#undef LDB
#undef MM
#undef BAR1
#undef BAR2

// ---------------- RoPE (in-place on Q and K, bf16) ----------------
__global__ __launch_bounds__(256) void rope_kernel(ushort* __restrict__ Q,
                                                   ushort* __restrict__ Kb,
                                                   const int* __restrict__ pos_ids,
                                                   int nrows) {
  int gid = blockIdx.x * 256 + threadIdx.x;
  int d = gid & 63;
  int row = gid >> 6;
  if (row >= nrows) return;
  int t = row >> 5;
  int pos = pos_ids[t];
  float inv = expf((float)d * -0.14391156831212788f);  // -ln(10000)/64
  float ang = (float)pos * inv;
  float s, c;
  sincosf(ang, &s, &c);
  size_t base = (size_t)row * HS;
  {
    float x1 = bf2f(Q[base + d]), x2 = bf2f(Q[base + d + 64]);
    Q[base + d]      = f2bf(x1 * c - x2 * s);
    Q[base + d + 64] = f2bf(x2 * c + x1 * s);
  }
  {
    float x1 = bf2f(Kb[base + d]), x2 = bf2f(Kb[base + d + 64]);
    Kb[base + d]      = f2bf(x1 * c - x2 * s);
    Kb[base + d + 64] = f2bf(x2 * c + x1 * s);
  }
}

// ---------------- Causal flash attention (v9, round-15 verified) ----------------
__global__ __launch_bounds__(512) void flash_attn(const ushort* __restrict__ Q,
                                                  const ushort* __restrict__ K,
                                                  const ushort* __restrict__ V,
                                                  ushort* __restrict__ O) {
  __shared__ __align__(16) ushort Ks[2][KVBLK * HS];
  __shared__ __align__(16) ushort Vs[2][KVBLK * HS];
  __shared__ __align__(16) ushort Ps[8][32 * 72];   // per-wave P^T tile: 32 rows x 144 B
  const int tid = threadIdx.x;
  const int w = tid >> 6, l = tid & 63, lhi = l >> 4, llo = l & 15;
  const int qbp = blockIdx.x, h = blockIdx.y;

  // tr-read per-lane constants (V path)
  const int g = llo >> 2, c = llo & 3;
  const int swz = g | ((lhi & 1) << 2);
  const int c1 = c >> 1;
  const int swL = swz & 1, swH = swz & 6;
  const unsigned trconst = (unsigned)((lhi * 8 + g) * 256 + ((c1 ^ swL) << 4) + (c & 1) * 8);

  // gld_lds staging constants
  const int r0 = w * 4 + lhi;
  const int cgK = llo ^ (r0 & 7);
  const int cgV = llo ^ ((r0 & 3) | (((r0 >> 3) & 1) << 2));

  char* pwB = (char*)Ps[w];
  const float scale = 0.08838834764831845f;  // 1/sqrt(128)

#define STAGE(T1) do { \
    const ushort* kp_ = K + (size_t)((T1) * KVBLK + r0) * CDIM + h * HS + cgK * 8; \
    const ushort* vp_ = V + (size_t)((T1) * KVBLK + r0) * CDIM + h * HS + cgV * 8; \
    char* kd_ = (char*)Ks[(T1) & 1] + w * 1024; \
    char* vd_ = (char*)Vs[(T1) & 1] + w * 1024; \
    gld16(kp_, kd_); gld16(kp_ + (size_t)32 * CDIM, kd_ + 8192); \
    gld16(vp_, vd_); gld16(vp_ + (size_t)32 * CDIM, vd_ + 8192); \
  } while (0)

  for (int ph = 0; ph < 2; ph++) {
    const int qt = ph ? (NQT - 1 - qbp) : qbp;
    const int qr0 = qt * QBLK + w * 32;
    const int ntile = 4 * qt + 4;

    short8 aq[2][4];
#pragma unroll
    for (int mf = 0; mf < 2; mf++) {
      const ushort* qp = Q + (size_t)(qr0 + mf * 16 + llo) * CDIM + h * HS + lhi * 8;
#pragma unroll
      for (int ki = 0; ki < 4; ki++) aq[mf][ki] = *(const short8*)(qp + ki * 32);
    }

    f32x4 acc[2][8] = {};
    float mrow[2] = {-1e30f, -1e30f};
    float lrow[2] = {0.f, 0.f};

    STAGE(0);
    __syncthreads();

    for (int t = 0; t < ntile; t++) {
      const int kv0 = t * KVBLK;
      if (t + 1 < ntile) STAGE(t + 1);

      const bool active = (kv0 <= qr0 + 31);
      if (active) {
        const char* ksB = (const char*)Ks[t & 1];
        const unsigned trb = lds_off(Vs[t & 1]) + trconst;

        // ---- S^T = K Q^T ----
        f32x4 s[2][4];
        __builtin_amdgcn_s_setprio(1);
#pragma unroll
        for (int nt = 0; nt < 4; nt++) {
          const int krow = nt * 16 + llo;
          const char* kr = ksB + krow * 256;
          short8 kf[4];
#pragma unroll
          for (int ki = 0; ki < 4; ki++)
            kf[ki] = *(const short8*)(kr + (((ki * 4 + lhi) ^ (krow & 7)) << 4));
          f32x4 s0 = {0.f, 0.f, 0.f, 0.f}, s1 = {0.f, 0.f, 0.f, 0.f};
#pragma unroll
          for (int ki = 0; ki < 4; ki++) {
            s0 = __builtin_amdgcn_mfma_f32_16x16x32_bf16(kf[ki], aq[0][ki], s0, 0, 0, 0);
            s1 = __builtin_amdgcn_mfma_f32_16x16x32_bf16(kf[ki], aq[1][ki], s1, 0, 0, 0);
          }
          s[0][nt] = s0; s[1][nt] = s1;
        }
        __builtin_amdgcn_s_setprio(0);

        // hoist V^T tr-reads for kv-block b=0
        short4v vl0[8], vh0[8];
#pragma unroll
        for (int on = 0; on < 8; on++) {
          unsigned a = trb + (unsigned)(((on * 2) ^ swH) << 4);
          vl0[on] = ds_tr16<0>(a);
          vh0[on] = ds_tr16<1024>(a);
        }

        // ---- scale + causal mask ----
        const bool needm = (kv0 + KVBLK - 1 > qr0);
#pragma unroll
        for (int mf = 0; mf < 2; mf++) {
          const int qi = qr0 + mf * 16 + llo;
#pragma unroll
          for (int nt = 0; nt < 4; nt++) {
            const int kvb = kv0 + nt * 16 + lhi * 4;
#pragma unroll
            for (int j = 0; j < 4; j++) {
              float sv = s[mf][nt][j] * scale;
              if (needm && kvb + j > qi) sv = -1e30f;
              s[mf][nt][j] = sv;
            }
          }
        }

        // ---- softmax: in-register row reduce + 2 shfl; defer-max ----
#pragma unroll
        for (int mf = 0; mf < 2; mf++) {
          f32x4 mm;
#pragma unroll
          for (int j = 0; j < 4; j++)
            mm[j] = fmaxf(fmaxf(s[mf][0][j], s[mf][1][j]), fmaxf(s[mf][2][j], s[mf][3][j]));
          float pmax = fmaxf(fmaxf(mm[0], mm[1]), fmaxf(mm[2], mm[3]));
          pmax = fmaxf(pmax, __shfl_xor(pmax, 16));
          pmax = fmaxf(pmax, __shfl_xor(pmax, 32));
          if (__any(pmax > mrow[mf] + 8.f)) {
            float mn = fmaxf(mrow[mf], pmax);
            float sc = __expf(mrow[mf] - mn);
            mrow[mf] = mn;
            lrow[mf] *= sc;
#pragma unroll
            for (int on = 0; on < 8; on++)
#pragma unroll
              for (int j = 0; j < 4; j++) acc[mf][on][j] *= sc;
          }
          float rs = 0.f;
#pragma unroll
          for (int nt = 0; nt < 4; nt++) {
            float p0 = __expf(s[mf][nt][0] - mrow[mf]);
            float p1 = __expf(s[mf][nt][1] - mrow[mf]);
            float p2 = __expf(s[mf][nt][2] - mrow[mf]);
            float p3 = __expf(s[mf][nt][3] - mrow[mf]);
            rs += (p0 + p1) + (p2 + p3);
            uint2 pk;
            pk.x = cvtpk_bf16(p0, p1);
            pk.y = cvtpk_bf16(p2, p3);
            *(uint2*)(pwB + (mf * 16 + llo) * 144 + nt * 32 + lhi * 8) = pk;
          }
          rs += __shfl_xor(rs, 16);
          rs += __shfl_xor(rs, 32);
          lrow[mf] += rs;
        }

        // ---- O^T += V^T P^T ----
        {
          short8 pf0 = *(const short8*)(pwB + llo * 144 + lhi * 16);
          short8 pf1 = *(const short8*)(pwB + (16 + llo) * 144 + lhi * 16);
          asm volatile("s_waitcnt lgkmcnt(0)" ::: "memory");
          __builtin_amdgcn_sched_barrier(0);
          __builtin_amdgcn_s_setprio(1);
#pragma unroll
          for (int on = 0; on < 8; on++) {
            short8 vf = __builtin_shufflevector(vl0[on], vh0[on], 0, 1, 2, 3, 4, 5, 6, 7);
            acc[0][on] = __builtin_amdgcn_mfma_f32_16x16x32_bf16(vf, pf0, acc[0][on], 0, 0, 0);
            acc[1][on] = __builtin_amdgcn_mfma_f32_16x16x32_bf16(vf, pf1, acc[1][on], 0, 0, 0);
          }
          __builtin_amdgcn_s_setprio(0);
        }
        {
          short8 pf0 = *(const short8*)(pwB + llo * 144 + 64 + lhi * 16);
          short8 pf1 = *(const short8*)(pwB + (16 + llo) * 144 + 64 + lhi * 16);
          short4v vl[8], vh[8];
#pragma unroll
          for (int on = 0; on < 8; on++) {
            unsigned a = trb + (unsigned)(((on * 2) ^ swH) << 4);
            vl[on] = ds_tr16<8192>(a);
            vh[on] = ds_tr16<9216>(a);
          }
          asm volatile("s_waitcnt lgkmcnt(0)" ::: "memory");
          __builtin_amdgcn_sched_barrier(0);
          __builtin_amdgcn_s_setprio(1);
#pragma unroll
          for (int on = 0; on < 8; on++) {
            short8 vf = __builtin_shufflevector(vl[on], vh[on], 0, 1, 2, 3, 4, 5, 6, 7);
            acc[0][on] = __builtin_amdgcn_mfma_f32_16x16x32_bf16(vf, pf0, acc[0][on], 0, 0, 0);
            acc[1][on] = __builtin_amdgcn_mfma_f32_16x16x32_bf16(vf, pf1, acc[1][on], 0, 0, 0);
          }
          __builtin_amdgcn_s_setprio(0);
        }
      }  // active

      __syncthreads();  // drains gld16 vmcnt + all LDS reads; next iter swaps buffers
    }

    // ---- epilogue ----
#pragma unroll
    for (int mf = 0; mf < 2; mf++) {
      const float ri = 1.0f / lrow[mf];
      ushort* orow = O + (size_t)(qr0 + mf * 16 + llo) * CDIM + h * HS + lhi * 4;
#pragma unroll
      for (int on = 0; on < 8; on++) {
        ushort4 o4;
        o4.x = f2bf(acc[mf][on][0] * ri);
        o4.y = f2bf(acc[mf][on][1] * ri);
        o4.z = f2bf(acc[mf][on][2] * ri);
        o4.w = f2bf(acc[mf][on][3] * ri);
        *(ushort4*)(orow + on * 16) = o4;
      }
    }
  }  // phase
#undef STAGE
}

// ---------------- launch ----------------
extern "C" void kernel_launch(void* const* d_in, const int* in_sizes, int n_in,
                              void* d_out, int out_size, void* d_ws, size_t ws_size,
                              hipStream_t stream) {
  const float* hs = (const float*)d_in[0];
  const int* pos = (const int*)d_in[1];
  const float* Wq = (const float*)d_in[2];
  const float* Wk = (const float*)d_in[3];
  const float* Wv = (const float*)d_in[4];
  const float* Wo = (const float*)d_in[5];
  float* out = (float*)d_out;

  const int T = 4096;
  const size_t elems = (size_t)T * CDIM;

  ushort* hsb  = (ushort*)d_ws;      // also attention output
  ushort* wbuf = hsb + elems;        // Wq bf16 / later Wo bf16
  ushort* qb   = wbuf + elems;
  ushort* kb   = qb + elems;
  ushort* vb   = kb + elems;

  // Wk/Wv bf16 scratch inside d_out (overwritten by the final GEMM)
  ushort* wkb = (ushort*)d_out;            // 32 MB
  ushort* wvb = wkb + elems;               // 32 MB

  const int n4 = (int)(elems / 4);
  const int castBlocks = (n4 + 255) / 256;

  cast4_kernel<<<castBlocks * 4, 256, 0, stream>>>(hs, Wq, Wk, Wv, hsb, wbuf, wkb, wvb, castBlocks);

  gemm_qkv<<<768, 512, 0, stream>>>(hsb, wbuf, wkb, wvb, qb, kb, vb);

  rope_kernel<<<(T * NH * 64) / 256, 256, 0, stream>>>(qb, kb, pos, T * NH);

  flash_attn<<<dim3(NQT / 2, NH), 512, 0, stream>>>(qb, kb, vb, hsb);

  cast_bf16_kernel<<<castBlocks, 256, 0, stream>>>(Wo, wbuf, n4);
  gemm256f<<<256, 512, 0, stream>>>(hsb, wbuf, out);
}

// Round 21
// 751.131 us; speedup vs baseline: 1.0945x; 1.0095x over previous
//
#include <hip/hip_runtime.h>

typedef __attribute__((ext_vector_type(8))) short short8;
typedef __attribute__((ext_vector_type(4))) short short4v;
typedef __attribute__((ext_vector_type(4))) float f32x4;

#define NH 32
#define HS 128
#define CDIM 4096
#define QBLK 256
#define KVBLK 64
#define NQT 16  // T / QBLK

__device__ __forceinline__ ushort f2bf(float f) {
  union { float f; unsigned u; } a; a.f = f;
  unsigned u = a.u;
  return (ushort)((u + 0x7FFFu + ((u >> 16) & 1u)) >> 16);
}
__device__ __forceinline__ float bf2f(ushort h) {
  union { unsigned u; float f; } a; a.u = ((unsigned)h) << 16;
  return a.f;
}
__device__ __forceinline__ unsigned cvtpk_bf16(float lo, float hi) {
  unsigned r;
  asm("v_cvt_pk_bf16_f32 %0, %1, %2" : "=v"(r) : "v"(lo), "v"(hi));
  return r;
}

__device__ __forceinline__ void gld16(const void* g, void* l) {
  __builtin_amdgcn_global_load_lds((const __attribute__((address_space(1))) void*)g,
                                   (__attribute__((address_space(3))) void*)l, 16, 0, 0);
}

__device__ __forceinline__ unsigned lds_off(const void* p) {
  return (unsigned)(uintptr_t)(const __attribute__((address_space(3))) void*)p;
}

template<int OFF>
__device__ __forceinline__ short4v ds_tr16(unsigned addr) {
  short4v r;
  asm volatile("ds_read_b64_tr_b16 %0, %1 offset:%c2" : "=v"(r) : "v"(addr), "i"(OFF));
  return r;
}

// ---------------- fp32 -> bf16 casts ----------------
__global__ __launch_bounds__(256) void cast4_kernel(const float* __restrict__ s0,
                                                    const float* __restrict__ s1,
                                                    const float* __restrict__ s2,
                                                    const float* __restrict__ s3,
                                                    ushort* __restrict__ d0,
                                                    ushort* __restrict__ d1,
                                                    ushort* __restrict__ d2,
                                                    ushort* __restrict__ d3,
                                                    int segBlocks) {
  int b = blockIdx.x;
  int seg = b / segBlocks;
  int i = (b - seg * segBlocks) * 256 + threadIdx.x;
  const float* in = (seg == 0) ? s0 : (seg == 1) ? s1 : (seg == 2) ? s2 : s3;
  ushort* out = (seg == 0) ? d0 : (seg == 1) ? d1 : (seg == 2) ? d2 : d3;
  float4 v = ((const float4*)in)[i];
  ushort4 o;
  o.x = f2bf(v.x); o.y = f2bf(v.y); o.z = f2bf(v.z); o.w = f2bf(v.w);
  ((ushort4*)out)[i] = o;
}

// ---------------- GEMM 256x256 8-phase core (round-18 verified: best state) ----------------
// 16x16x32 MFMA. Swizzle cl = cg ^ (row & 7) (bank conflicts = 0).
// ds_reads for P2/P3/P6/P7 hoisted into the previous phase after its MFMA cluster;
// staging 2 gld16/phase; vmcnt(6)@P4 / vmcnt(8)@P8.
// 32x32x16 conversion regressed (round 19: lane->row read map reintroduced 3.77e7
// bank conflicts) — keep 16x16. LDS-pipe accounting: per 1091-cy phase, MFMA 516 cy,
// LDS reads ~576 + staging writes ~256 -> LDS-BW-subscribed at this layout.
#define A00 0
#define A01 16384
#define A10 32768
#define A11 49152
#define B00 65536
#define B01 81920
#define B10 98304
#define B11 114688

#define GEMM_BODY(OUT_STORE)                                                       \
  __shared__ char sm[131072];                                                      \
  const int tid = threadIdx.x;                                                     \
  const int w = tid >> 6, lane = tid & 63, lhi = lane >> 4, llo = lane & 15;       \
  const char* A0p = (const char*)(A + m0 * 4096);                                  \
  const char* A1p = A0p + 1048576;                                                 \
  const char* B0p = (const char*)(Bp + n0 * 4096);                                 \
  const char* B1p = B0p + 1048576;                                                 \
  const int i0 = tid, i1 = tid + 512;                                              \
  const int ri0 = i0 >> 3, ri1 = i1 >> 3;                                          \
  const int cg0 = (i0 & 7) ^ (ri0 & 7);                                            \
  const int cg1 = (i1 & 7) ^ (ri1 & 7);                                            \
  const int off0 = ri0 * 8192 + cg0 * 16;                                          \
  const int off1 = ri1 * 8192 + cg1 * 16;                                          \
  const unsigned sd0 = (unsigned)(w * 1024);                                       \
  const unsigned sd1 = (unsigned)(8192 + w * 1024);                                \
  const int sw = llo & 7;                                                          \
  const unsigned rd0 = (unsigned)(llo * 128 + (((0 * 4 + lhi) ^ sw) << 4));        \
  const unsigned rd1 = (unsigned)(llo * 128 + (((1 * 4 + lhi) ^ sw) << 4));        \
  const int wmg = w >> 2, wng = w & 3;                                             \
  const unsigned aE = wmg ? A01 : A00;                                             \
  const unsigned aO = wmg ? A11 : A10;                                             \
  const unsigned bE = (wng >> 1) ? B01 : B00;                                      \
  const unsigned bO = (wng >> 1) ? B11 : B10;                                      \
  const unsigned bco = (unsigned)((wng & 1) * 8192);                               \
  f32x4 acc[8][4] = {};                                                            \
  short8 a0[4], a1[4], u0[2], u1[2], v0[2], v1[2];                                 \
  STG(B0p, 0, B00); STG(B1p, 0, B01); STG(A0p, 0, A00); STG(A1p, 0, A01);          \
  STG(B0p, 64, B10); STG(B1p, 64, B11); STG(A0p, 64, A10); STG(A1p, 64, A11);      \
  asm volatile("s_waitcnt vmcnt(8)" ::: "memory");                                 \
  __builtin_amdgcn_s_barrier();                                                    \
  __builtin_amdgcn_sched_barrier(0);                                               \
  for (int it = 0; it < 32; ++it) {                                                \
    const int kc = it * 128;                                                       \
    const bool st = (it < 31);                                                     \
    /* P1 */                                                                       \
    LDA(aE, 0); LDB(u0, u1, bE, 0);                                                \
    BAR1; MM(0, 0, u0, u1);                                                        \
    LDB(v0, v1, bE, 1);                                                            \
    BAR2;                                                                          \
    /* P2 */                                                                       \
    if (st) STG(B0p, kc + 128, B00);                                               \
    BAR1; MM(0, 1, v0, v1);                                                        \
    LDA(aE, 1);                                                                    \
    BAR2;                                                                          \
    /* P3 */                                                                       \
    if (st) STG(B1p, kc + 128, B01);                                               \
    BAR1; MM(1, 1, v0, v1); BAR2;                                                  \
    /* P4 */                                                                       \
    if (st) STG(A0p, kc + 128, A00);                                               \
    BAR1; MM(1, 0, u0, u1);                                                        \
    __builtin_amdgcn_s_setprio(0);                                                 \
    if (st) asm volatile("s_waitcnt vmcnt(6)" ::: "memory");                       \
    else    asm volatile("s_waitcnt vmcnt(0)" ::: "memory");                       \
    __builtin_amdgcn_s_barrier();                                                  \
    /* P5 */                                                                       \
    LDA(aO, 0); LDB(u0, u1, bO, 0);                                                \
    if (st) STG(A1p, kc + 128, A01);                                               \
    BAR1; MM(0, 0, u0, u1);                                                        \
    LDB(v0, v1, bO, 1);                                                            \
    BAR2;                                                                          \
    /* P6 */                                                                       \
    if (st) STG(B0p, kc + 192, B10);                                               \
    BAR1; MM(0, 1, v0, v1);                                                        \
    LDA(aO, 1);                                                                    \
    BAR2;                                                                          \
    /* P7 */                                                                       \
    if (st) STG(B1p, kc + 192, B11);                                               \
    BAR1; MM(1, 1, v0, v1); BAR2;                                                  \
    /* P8 */                                                                       \
    if (st) { STG(A0p, kc + 192, A10); STG(A1p, kc + 192, A11); }                  \
    BAR1; MM(1, 0, u0, u1);                                                        \
    __builtin_amdgcn_s_setprio(0);                                                 \
    if (st) asm volatile("s_waitcnt vmcnt(8)" ::: "memory");                       \
    __builtin_amdgcn_s_barrier();                                                  \
  }                                                                                \
  const int wm = wmg * 128, wn = wng * 64;                                         \
  _Pragma("unroll")                                                                \
  for (int m = 0; m < 8; m++) {                                                    \
    _Pragma("unroll")                                                              \
    for (int nf = 0; nf < 4; nf++) {                                               \
      const size_t col = n0 + wn + nf * 16 + llo;                                  \
      _Pragma("unroll")                                                            \
      for (int j = 0; j < 4; j++) {                                                \
        const size_t row = m0 + wm + m * 16 + lhi * 4 + j;                         \
        OUT_STORE;                                                                 \
      }                                                                            \
    }                                                                              \
  }

#define STG(PAN, K0, LB) do { \
    gld16((PAN) + (size_t)(K0) * 2 + off0, sm + (LB) + sd0); \
    gld16((PAN) + (size_t)(K0) * 2 + off1, sm + (LB) + sd1); \
  } while (0)
#define LDA(BASE, MQ) do { _Pragma("unroll") for (int m_ = 0; m_ < 4; m_++) { \
    a0[m_] = *(const short8*)(sm + (BASE) + (MQ) * 8192 + m_ * 2048 + rd0); \
    a1[m_] = *(const short8*)(sm + (BASE) + (MQ) * 8192 + m_ * 2048 + rd1); } } while (0)
#define LDB(R0, R1, BASE, NQ) do { _Pragma("unroll") for (int n_ = 0; n_ < 2; n_++) { \
    R0[n_] = *(const short8*)(sm + (BASE) + bco + (NQ) * 4096 + n_ * 2048 + rd0); \
    R1[n_] = *(const short8*)(sm + (BASE) + bco + (NQ) * 4096 + n_ * 2048 + rd1); } } while (0)
#define MM(MQ, NQ, R0, R1) do { \
    _Pragma("unroll") for (int m_ = 0; m_ < 4; m_++) _Pragma("unroll") for (int n_ = 0; n_ < 2; n_++) \
      acc[(MQ) * 4 + m_][(NQ) * 2 + n_] = __builtin_amdgcn_mfma_f32_16x16x32_bf16(a0[m_], R0[n_], acc[(MQ) * 4 + m_][(NQ) * 2 + n_], 0, 0, 0); \
    _Pragma("unroll") for (int m_ = 0; m_ < 4; m_++) _Pragma("unroll") for (int n_ = 0; n_ < 2; n_++) \
      acc[(MQ) * 4 + m_][(NQ) * 2 + n_] = __builtin_amdgcn_mfma_f32_16x16x32_bf16(a1[m_], R1[n_], acc[(MQ) * 4 + m_][(NQ) * 2 + n_], 0, 0, 0); \
  } while (0)
#define BAR1 do { __builtin_amdgcn_s_barrier(); \
    __builtin_amdgcn_s_setprio(1); } while (0)
#define BAR2 do { __builtin_amdgcn_s_setprio(0); __builtin_amdgcn_s_barrier(); } while (0)

// Fused QKV projection: segment-ordered (bid 0-255 Q, 256-511 K, 512-767 V).
__global__ __launch_bounds__(512, 2) void gemm_qkv(const ushort* __restrict__ A,
                                                   const ushort* __restrict__ Bq,
                                                   const ushort* __restrict__ Bk,
                                                   const ushort* __restrict__ Bv,
                                                   ushort* __restrict__ Cq,
                                                   ushort* __restrict__ Ck,
                                                   ushort* __restrict__ Cv) {
  const int bid = blockIdx.x;
  const int seg = bid >> 8;
  const int lb = bid & 255;
  const int x = (lb & 7) * 32 + (lb >> 3);
  const int mt = x >> 4, ntl = x & 15;
  const ushort* Bp;
  ushort* Cp;
  if (seg == 0)      { Bp = Bq; Cp = Cq; }
  else if (seg == 1) { Bp = Bk; Cp = Ck; }
  else               { Bp = Bv; Cp = Cv; }
  const size_t m0 = (size_t)mt * 256, n0 = (size_t)ntl * 256;
  GEMM_BODY(Cp[row * 4096 + col] = f2bf(acc[m][nf][j]));
}

// Single GEMM (final O-projection, fp32 out).
__global__ __launch_bounds__(512, 2) void gemm256f(const ushort* __restrict__ A,
                                                   const ushort* __restrict__ Bp,
                                                   float* __restrict__ C) {
  const int bid = blockIdx.x;
  const int x = (bid & 7) * 32 + (bid >> 3);
  const int mt = x >> 4, nt = x & 15;
  const size_t m0 = (size_t)mt * 256, n0 = (size_t)nt * 256;
  GEMM_BODY(C[row * 4096 + col] = acc[m][nf][j]);
}

#undef STG
#undef LDA
#undef LDB
#undef MM
#undef BAR1
#undef BAR2

// ---------------- fused RoPE (Q,K in-place) + Wo fp32->bf16 cast ----------------
// blocks [0, ropeBlocks): RoPE; blocks [ropeBlocks, +castBlocks): cast Wo -> wob.
// Both HBM-bound and independent; merging removes one serial dispatch gap.
__global__ __launch_bounds__(256) void rope_castwo_kernel(ushort* __restrict__ Q,
                                                          ushort* __restrict__ Kb,
                                                          const int* __restrict__ pos_ids,
                                                          const float* __restrict__ Wo,
                                                          ushort* __restrict__ wob,
                                                          int ropeBlocks, int nrows, int n4) {
  const int b = blockIdx.x;
  if (b >= ropeBlocks) {
    int i = (b - ropeBlocks) * 256 + threadIdx.x;
    if (i < n4) {
      float4 v = ((const float4*)Wo)[i];
      ushort4 o;
      o.x = f2bf(v.x); o.y = f2bf(v.y); o.z = f2bf(v.z); o.w = f2bf(v.w);
      ((ushort4*)wob)[i] = o;
    }
    return;
  }
  int gid = b * 256 + threadIdx.x;
  int d = gid & 63;
  int row = gid >> 6;
  if (row >= nrows) return;
  int t = row >> 5;
  int pos = pos_ids[t];
  float inv = expf((float)d * -0.14391156831212788f);  // -ln(10000)/64
  float ang = (float)pos * inv;
  float s, c;
  sincosf(ang, &s, &c);
  size_t base = (size_t)row * HS;
  {
    float x1 = bf2f(Q[base + d]), x2 = bf2f(Q[base + d + 64]);
    Q[base + d]      = f2bf(x1 * c - x2 * s);
    Q[base + d + 64] = f2bf(x2 * c + x1 * s);
  }
  {
    float x1 = bf2f(Kb[base + d]), x2 = bf2f(Kb[base + d + 64]);
    Kb[base + d]      = f2bf(x1 * c - x2 * s);
    Kb[base + d + 64] = f2bf(x2 * c + x1 * s);
  }
}

// ---------------- Causal flash attention (v9, round-15 verified) ----------------
__global__ __launch_bounds__(512) void flash_attn(const ushort* __restrict__ Q,
                                                  const ushort* __restrict__ K,
                                                  const ushort* __restrict__ V,
                                                  ushort* __restrict__ O) {
  __shared__ __align__(16) ushort Ks[2][KVBLK * HS];
  __shared__ __align__(16) ushort Vs[2][KVBLK * HS];
  __shared__ __align__(16) ushort Ps[8][32 * 72];   // per-wave P^T tile: 32 rows x 144 B
  const int tid = threadIdx.x;
  const int w = tid >> 6, l = tid & 63, lhi = l >> 4, llo = l & 15;
  const int qbp = blockIdx.x, h = blockIdx.y;

  // tr-read per-lane constants (V path)
  const int g = llo >> 2, c = llo & 3;
  const int swz = g | ((lhi & 1) << 2);
  const int c1 = c >> 1;
  const int swL = swz & 1, swH = swz & 6;
  const unsigned trconst = (unsigned)((lhi * 8 + g) * 256 + ((c1 ^ swL) << 4) + (c & 1) * 8);

  // gld_lds staging constants
  const int r0 = w * 4 + lhi;
  const int cgK = llo ^ (r0 & 7);
  const int cgV = llo ^ ((r0 & 3) | (((r0 >> 3) & 1) << 2));

  char* pwB = (char*)Ps[w];
  const float scale = 0.08838834764831845f;  // 1/sqrt(128)

#define STAGE(T1) do { \
    const ushort* kp_ = K + (size_t)((T1) * KVBLK + r0) * CDIM + h * HS + cgK * 8; \
    const ushort* vp_ = V + (size_t)((T1) * KVBLK + r0) * CDIM + h * HS + cgV * 8; \
    char* kd_ = (char*)Ks[(T1) & 1] + w * 1024; \
    char* vd_ = (char*)Vs[(T1) & 1] + w * 1024; \
    gld16(kp_, kd_); gld16(kp_ + (size_t)32 * CDIM, kd_ + 8192); \
    gld16(vp_, vd_); gld16(vp_ + (size_t)32 * CDIM, vd_ + 8192); \
  } while (0)

  for (int ph = 0; ph < 2; ph++) {
    const int qt = ph ? (NQT - 1 - qbp) : qbp;
    const int qr0 = qt * QBLK + w * 32;
    const int ntile = 4 * qt + 4;

    short8 aq[2][4];
#pragma unroll
    for (int mf = 0; mf < 2; mf++) {
      const ushort* qp = Q + (size_t)(qr0 + mf * 16 + llo) * CDIM + h * HS + lhi * 8;
#pragma unroll
      for (int ki = 0; ki < 4; ki++) aq[mf][ki] = *(const short8*)(qp + ki * 32);
    }

    f32x4 acc[2][8] = {};
    float mrow[2] = {-1e30f, -1e30f};
    float lrow[2] = {0.f, 0.f};

    STAGE(0);
    __syncthreads();

    for (int t = 0; t < ntile; t++) {
      const int kv0 = t * KVBLK;
      if (t + 1 < ntile) STAGE(t + 1);

      const bool active = (kv0 <= qr0 + 31);
      if (active) {
        const char* ksB = (const char*)Ks[t & 1];
        const unsigned trb = lds_off(Vs[t & 1]) + trconst;

        // ---- S^T = K Q^T ----
        f32x4 s[2][4];
        __builtin_amdgcn_s_setprio(1);
#pragma unroll
        for (int nt = 0; nt < 4; nt++) {
          const int krow = nt * 16 + llo;
          const char* kr = ksB + krow * 256;
          short8 kf[4];
#pragma unroll
          for (int ki = 0; ki < 4; ki++)
            kf[ki] = *(const short8*)(kr + (((ki * 4 + lhi) ^ (krow & 7)) << 4));
          f32x4 s0 = {0.f, 0.f, 0.f, 0.f}, s1 = {0.f, 0.f, 0.f, 0.f};
#pragma unroll
          for (int ki = 0; ki < 4; ki++) {
            s0 = __builtin_amdgcn_mfma_f32_16x16x32_bf16(kf[ki], aq[0][ki], s0, 0, 0, 0);
            s1 = __builtin_amdgcn_mfma_f32_16x16x32_bf16(kf[ki], aq[1][ki], s1, 0, 0, 0);
          }
          s[0][nt] = s0; s[1][nt] = s1;
        }
        __builtin_amdgcn_s_setprio(0);

        // hoist V^T tr-reads for kv-block b=0
        short4v vl0[8], vh0[8];
#pragma unroll
        for (int on = 0; on < 8; on++) {
          unsigned a = trb + (unsigned)(((on * 2) ^ swH) << 4);
          vl0[on] = ds_tr16<0>(a);
          vh0[on] = ds_tr16<1024>(a);
        }

        // ---- scale + causal mask ----
        const bool needm = (kv0 + KVBLK - 1 > qr0);
#pragma unroll
        for (int mf = 0; mf < 2; mf++) {
          const int qi = qr0 + mf * 16 + llo;
#pragma unroll
          for (int nt = 0; nt < 4; nt++) {
            const int kvb = kv0 + nt * 16 + lhi * 4;
#pragma unroll
            for (int j = 0; j < 4; j++) {
              float sv = s[mf][nt][j] * scale;
              if (needm && kvb + j > qi) sv = -1e30f;
              s[mf][nt][j] = sv;
            }
          }
        }

        // ---- softmax: in-register row reduce + 2 shfl; defer-max ----
#pragma unroll
        for (int mf = 0; mf < 2; mf++) {
          f32x4 mm;
#pragma unroll
          for (int j = 0; j < 4; j++)
            mm[j] = fmaxf(fmaxf(s[mf][0][j], s[mf][1][j]), fmaxf(s[mf][2][j], s[mf][3][j]));
          float pmax = fmaxf(fmaxf(mm[0], mm[1]), fmaxf(mm[2], mm[3]));
          pmax = fmaxf(pmax, __shfl_xor(pmax, 16));
          pmax = fmaxf(pmax, __shfl_xor(pmax, 32));
          if (__any(pmax > mrow[mf] + 8.f)) {
            float mn = fmaxf(mrow[mf], pmax);
            float sc = __expf(mrow[mf] - mn);
            mrow[mf] = mn;
            lrow[mf] *= sc;
#pragma unroll
            for (int on = 0; on < 8; on++)
#pragma unroll
              for (int j = 0; j < 4; j++) acc[mf][on][j] *= sc;
          }
          float rs = 0.f;
#pragma unroll
          for (int nt = 0; nt < 4; nt++) {
            float p0 = __expf(s[mf][nt][0] - mrow[mf]);
            float p1 = __expf(s[mf][nt][1] - mrow[mf]);
            float p2 = __expf(s[mf][nt][2] - mrow[mf]);
            float p3 = __expf(s[mf][nt][3] - mrow[mf]);
            rs += (p0 + p1) + (p2 + p3);
            uint2 pk;
            pk.x = cvtpk_bf16(p0, p1);
            pk.y = cvtpk_bf16(p2, p3);
            *(uint2*)(pwB + (mf * 16 + llo) * 144 + nt * 32 + lhi * 8) = pk;
          }
          rs += __shfl_xor(rs, 16);
          rs += __shfl_xor(rs, 32);
          lrow[mf] += rs;
        }

        // ---- O^T += V^T P^T ----
        {
          short8 pf0 = *(const short8*)(pwB + llo * 144 + lhi * 16);
          short8 pf1 = *(const short8*)(pwB + (16 + llo) * 144 + lhi * 16);
          asm volatile("s_waitcnt lgkmcnt(0)" ::: "memory");
          __builtin_amdgcn_sched_barrier(0);
          __builtin_amdgcn_s_setprio(1);
#pragma unroll
          for (int on = 0; on < 8; on++) {
            short8 vf = __builtin_shufflevector(vl0[on], vh0[on], 0, 1, 2, 3, 4, 5, 6, 7);
            acc[0][on] = __builtin_amdgcn_mfma_f32_16x16x32_bf16(vf, pf0, acc[0][on], 0, 0, 0);
            acc[1][on] = __builtin_amdgcn_mfma_f32_16x16x32_bf16(vf, pf1, acc[1][on], 0, 0, 0);
          }
          __builtin_amdgcn_s_setprio(0);
        }
        {
          short8 pf0 = *(const short8*)(pwB + llo * 144 + 64 + lhi * 16);
          short8 pf1 = *(const short8*)(pwB + (16 + llo) * 144 + 64 + lhi * 16);
          short4v vl[8], vh[8];
#pragma unroll
          for (int on = 0; on < 8; on++) {
            unsigned a = trb + (unsigned)(((on * 2) ^ swH) << 4);
            vl[on] = ds_tr16<8192>(a);
            vh[on] = ds_tr16<9216>(a);
          }
          asm volatile("s_waitcnt lgkmcnt(0)" ::: "memory");
          __builtin_amdgcn_sched_barrier(0);
          __builtin_amdgcn_s_setprio(1);
#pragma unroll
          for (int on = 0; on < 8; on++) {
            short8 vf = __builtin_shufflevector(vl[on], vh[on], 0, 1, 2, 3, 4, 5, 6, 7);
            acc[0][on] = __builtin_amdgcn_mfma_f32_16x16x32_bf16(vf, pf0, acc[0][on], 0, 0, 0);
            acc[1][on] = __builtin_amdgcn_mfma_f32_16x16x32_bf16(vf, pf1, acc[1][on], 0, 0, 0);
          }
          __builtin_amdgcn_s_setprio(0);
        }
      }  // active

      __syncthreads();  // drains gld16 vmcnt + all LDS reads; next iter swaps buffers
    }

    // ---- epilogue ----
#pragma unroll
    for (int mf = 0; mf < 2; mf++) {
      const float ri = 1.0f / lrow[mf];
      ushort* orow = O + (size_t)(qr0 + mf * 16 + llo) * CDIM + h * HS + lhi * 4;
#pragma unroll
      for (int on = 0; on < 8; on++) {
        ushort4 o4;
        o4.x = f2bf(acc[mf][on][0] * ri);
        o4.y = f2bf(acc[mf][on][1] * ri);
        o4.z = f2bf(acc[mf][on][2] * ri);
        o4.w = f2bf(acc[mf][on][3] * ri);
        *(ushort4*)(orow + on * 16) = o4;
      }
    }
  }  // phase
#undef STAGE
}

// ---------------- launch ----------------
extern "C" void kernel_launch(void* const* d_in, const int* in_sizes, int n_in,
                              void* d_out, int out_size, void* d_ws, size_t ws_size,
                              hipStream_t stream) {
  const float* hs = (const float*)d_in[0];
  const int* pos = (const int*)d_in[1];
  const float* Wq = (const float*)d_in[2];
  const float* Wk = (const float*)d_in[3];
  const float* Wv = (const float*)d_in[4];
  const float* Wo = (const float*)d_in[5];
  float* out = (float*)d_out;

  const int T = 4096;
  const size_t elems = (size_t)T * CDIM;

  ushort* hsb  = (ushort*)d_ws;      // also attention output
  ushort* wbuf = hsb + elems;        // Wq bf16 / later Wo bf16
  ushort* qb   = wbuf + elems;
  ushort* kb   = qb + elems;
  ushort* vb   = kb + elems;

  // Wk/Wv bf16 scratch inside d_out (overwritten by the final GEMM)
  ushort* wkb = (ushort*)d_out;            // 32 MB
  ushort* wvb = wkb + elems;               // 32 MB

  const int n4 = (int)(elems / 4);
  const int castBlocks = (n4 + 255) / 256;
  const int ropeBlocks = (T * NH * 64) / 256;

  cast4_kernel<<<castBlocks * 4, 256, 0, stream>>>(hs, Wq, Wk, Wv, hsb, wbuf, wkb, wvb, castBlocks);

  gemm_qkv<<<768, 512, 0, stream>>>(hsb, wbuf, wkb, wvb, qb, kb, vb);

  // RoPE(Q,K) + cast Wo->wbuf in one dispatch (wbuf free after gemm_qkv consumed Wq)
  rope_castwo_kernel<<<ropeBlocks + castBlocks, 256, 0, stream>>>(
      qb, kb, pos, Wo, wbuf, ropeBlocks, T * NH, n4);

  flash_attn<<<dim3(NQT / 2, NH), 512, 0, stream>>>(qb, kb, vb, hsb);

  gemm256f<<<256, 512, 0, stream>>>(hsb, wbuf, out);
}